// Round 2
// baseline (3660.653 us; speedup 1.0000x reference)
//
#include <hip/hip_runtime.h>

typedef __attribute__((ext_vector_type(8))) short bf16x8;
typedef __attribute__((ext_vector_type(4))) float f32x4;

#define L_DIM 24
#define B_DIM 32
#define S_DIM 512
#define H_DIM 1024
#define M_DIM 16384      // B*S
#define K_DIM 24576      // L*H
#define N_REAL 900
#define N_PAD 960
#define K2_PAD 912

#define BM 128
#define BN 64
#define BK 64

// round-to-nearest-even fp32 -> bf16
__device__ __forceinline__ short f2bf(float f) {
  unsigned u = __builtin_bit_cast(unsigned, f);
  u += 0x7FFFu + ((u >> 16) & 1u);
  return (short)(u >> 16);
}

// ---------------- P1: W1 [24576][900] fp32 -> W1T bf16 [960][24576], zero-padded
__global__ __launch_bounds__(256)
void prep_w1t_kernel(const float* __restrict__ w1, unsigned short* __restrict__ w1t) {
  __shared__ unsigned short t[64][72];
  const int n0 = blockIdx.x * 64;
  const int k0 = blockIdx.y * 64;
  const int tid = threadIdx.x;
  {
    const int nl = tid & 63;
    const int n = n0 + nl;
#pragma unroll
    for (int p = 0; p < 16; ++p) {
      const int kl = p * 4 + (tid >> 6);
      float v = (n < N_REAL) ? w1[(size_t)(k0 + kl) * N_REAL + n] : 0.f;
      t[nl][kl] = (unsigned short)f2bf(v);
    }
  }
  __syncthreads();
  {
    const int kl = tid & 63;
#pragma unroll
    for (int p = 0; p < 16; ++p) {
      const int nl2 = p * 4 + (tid >> 6);
      w1t[(size_t)(n0 + nl2) * K_DIM + k0 + kl] = t[nl2][kl];
    }
  }
}

// ---------------- P2: W2T fp32 [40][912] (transposed, padded) + b1 padded [960]
__global__ __launch_bounds__(256)
void prep_small_kernel(const float* __restrict__ w2, const float* __restrict__ b1,
                       float* __restrict__ w2t, float* __restrict__ b1p) {
  const int i = blockIdx.x * 256 + threadIdx.x;
  if (i < 40 * K2_PAD) {
    const int j = i / K2_PAD, k = i - j * K2_PAD;
    w2t[i] = (k < N_REAL) ? w2[(size_t)k * 40 + j] : 0.f;
  }
  const int t2 = i - 40 * K2_PAD;
  if (t2 >= 0 && t2 < N_PAD)
    b1p[t2] = (t2 < N_REAL) ? b1[t2] : 0.f;
}

// ---------------- G1: h1 = relu(x @ W1 + b1), bf16 MFMA, reg-staged + convert
__global__ __launch_bounds__(256)
void gemm1_kernel(const float* __restrict__ hs,
                  const unsigned short* __restrict__ w1t,
                  const float* __restrict__ b1p,
                  float* __restrict__ h1) {
  __shared__ __align__(16) unsigned short Ab[BM * BK];
  __shared__ __align__(16) unsigned short Bb[BN * BK];
  char* AbRaw = (char*)Ab;
  char* BbRaw = (char*)Bb;

  const int tid = threadIdx.x;
  const int lane = tid & 63;
  const int wid = tid >> 6;
  const int wr = wid >> 1;   // 0..1 : m-half (64 rows)
  const int wc = wid & 1;    // 0..1 : n-half (32 cols)

  const int m0 = blockIdx.y * BM;
  const int n0 = blockIdx.x * BN;

  f32x4 acc[4][2] = {};

  // A staging: thread -> (row, k-half of 32)
  const int arow = tid >> 1;
  const int ahalf = tid & 1;
  const int am = m0 + arow;
  const size_t a_row_off = (((size_t)(am >> 9)) * S_DIM + (am & 511)) * H_DIM;

  // B staging: thread -> (row, 16-elem quarter)
  const int brow = tid >> 2;
  const int bq = tid & 3;
  const unsigned short* w1row = w1t + (size_t)(n0 + brow) * K_DIM;

  for (int k0 = 0; k0 < K_DIM; k0 += BK) {
    // stage A: 32 fp32 -> 32 bf16 per thread (4 x b128 writes)
    {
      const int l = k0 >> 10;
      const int h0 = (k0 & 1023) + ahalf * 32;
      const float* aptr = hs + (size_t)l * (B_DIM * S_DIM * H_DIM) + a_row_off + h0;
#pragma unroll
      for (int j = 0; j < 4; ++j) {
        float4 f0 = *(const float4*)(aptr + j * 8);
        float4 f1 = *(const float4*)(aptr + j * 8 + 4);
        bf16x8 p;
        p[0] = f2bf(f0.x); p[1] = f2bf(f0.y); p[2] = f2bf(f0.z); p[3] = f2bf(f0.w);
        p[4] = f2bf(f1.x); p[5] = f2bf(f1.y); p[6] = f2bf(f1.z); p[7] = f2bf(f1.w);
        const int off = ((arow << 7) + ahalf * 64 + j * 16) ^ ((arow & 7) << 4);
        *(bf16x8*)(AbRaw + off) = p;
      }
    }
    // stage B: 16 bf16 x2 per thread (already bf16 in W1T)
    {
      const uint4 s0 = *(const uint4*)(w1row + k0 + bq * 16);
      const uint4 s1 = *(const uint4*)(w1row + k0 + bq * 16 + 8);
      const int off0 = ((brow << 7) + bq * 32) ^ ((brow & 7) << 4);
      const int off1 = ((brow << 7) + bq * 32 + 16) ^ ((brow & 7) << 4);
      *(uint4*)(BbRaw + off0) = s0;
      *(uint4*)(BbRaw + off1) = s1;
    }
    __syncthreads();

#pragma unroll
    for (int kk = 0; kk < 2; ++kk) {
      bf16x8 a[4], b[2];
#pragma unroll
      for (int mi = 0; mi < 4; ++mi) {
        const int row = wr * 64 + mi * 16 + (lane & 15);
        const int off = ((row << 7) + kk * 64 + (lane >> 4) * 16) ^ ((row & 7) << 4);
        a[mi] = *(const bf16x8*)(AbRaw + off);
      }
#pragma unroll
      for (int ni = 0; ni < 2; ++ni) {
        const int row = wc * 32 + ni * 16 + (lane & 15);
        const int off = ((row << 7) + kk * 64 + (lane >> 4) * 16) ^ ((row & 7) << 4);
        b[ni] = *(const bf16x8*)(BbRaw + off);
      }
#pragma unroll
      for (int mi = 0; mi < 4; ++mi)
#pragma unroll
        for (int ni = 0; ni < 2; ++ni)
          acc[mi][ni] = __builtin_amdgcn_mfma_f32_16x16x32_bf16(a[mi], b[ni], acc[mi][ni], 0, 0, 0);
    }
    __syncthreads();
  }

  // epilogue: relu(acc + b1), C/D layout: col = lane&15, row = (lane>>4)*4 + r
#pragma unroll
  for (int mi = 0; mi < 4; ++mi) {
#pragma unroll
    for (int ni = 0; ni < 2; ++ni) {
      const int n = n0 + wc * 32 + ni * 16 + (lane & 15);
      const float bias = b1p[n];
#pragma unroll
      for (int r = 0; r < 4; ++r) {
        const int m = m0 + wr * 64 + mi * 16 + (lane >> 4) * 4 + r;
        const float v = acc[mi][ni][r] + bias;
        h1[(size_t)m * N_PAD + n] = v > 0.f ? v : 0.f;
      }
    }
  }
}

// ---------------- K2: logits = sigmoid(relu(h1 @ W2 + b2) @ W3 + b3), one wave/row
__global__ __launch_bounds__(256)
void layer23_kernel(const float* __restrict__ h1, const float* __restrict__ w2t,
                    const float* __restrict__ b2, const float* __restrict__ w3,
                    const float* __restrict__ b3, float* __restrict__ logits) {
  const int wave = (blockIdx.x * 256 + threadIdx.x) >> 6;
  const int lane = threadIdx.x & 63;
  const float* hrow = h1 + (size_t)wave * N_PAD;
  float acc = 0.f;
  if (lane < 40) {
    const float* wrow = w2t + lane * K2_PAD;
    for (int k = 0; k < K2_PAD; k += 8) {
      float4 h0 = *(const float4*)(hrow + k);
      float4 h4 = *(const float4*)(hrow + k + 4);
      float4 w0 = *(const float4*)(wrow + k);
      float4 w4 = *(const float4*)(wrow + k + 4);
      acc += h0.x * w0.x + h0.y * w0.y + h0.z * w0.z + h0.w * w0.w;
      acc += h4.x * w4.x + h4.y * w4.y + h4.z * w4.z + h4.w * w4.w;
    }
    acc += b2[lane];
    acc = acc > 0.f ? acc : 0.f;
    acc *= w3[lane];
  }
#pragma unroll
  for (int off = 32; off > 0; off >>= 1)
    acc += __shfl_down(acc, off);
  if (lane == 0)
    logits[wave] = 1.f / (1.f + expf(-(acc + b3[0])));
}

// ---------------- K3: ragged gather
__global__ __launch_bounds__(256)
void gather_kernel(const int* __restrict__ starts, const float* __restrict__ logits,
                   float* __restrict__ out) {
  const int i = blockIdx.x * 256 + threadIdx.x;
  if (i >= M_DIM) return;
  const int st = starts[i];
  int idx = st;
  if (idx < 0) idx = 0;
  if (idx > S_DIM - 1) idx = S_DIM - 1;
  out[i] = (st != 0) ? logits[((i >> 9) << 9) + idx] : 0.f;
}

extern "C" void kernel_launch(void* const* d_in, const int* in_sizes, int n_in,
                              void* d_out, int out_size, void* d_ws, size_t ws_size,
                              hipStream_t stream) {
  const float* hs = (const float*)d_in[0];
  const float* W1 = (const float*)d_in[1];
  const float* b1 = (const float*)d_in[2];
  const float* W2 = (const float*)d_in[3];
  const float* b2 = (const float*)d_in[4];
  const float* W3 = (const float*)d_in[5];
  const float* b3 = (const float*)d_in[6];
  const int* starts = (const int*)d_in[7];
  float* out = (float*)d_out;

  char* ws = (char*)d_ws;
  unsigned short* w1t = (unsigned short*)ws;                              // 47,185,920 B
  float* h1 = (float*)(ws + 47185920);                                    // 62,914,560 B
  float* w2t = (float*)(ws + 47185920 + 62914560);                        // 145,920 B
  float* b1p = (float*)(ws + 47185920 + 62914560 + 145920);               // 3,840 B
  float* logits = (float*)(ws + 47185920 + 62914560 + 145920 + 3840);     // 65,536 B

  prep_w1t_kernel<<<dim3(15, 384), 256, 0, stream>>>(W1, w1t);
  prep_small_kernel<<<147, 256, 0, stream>>>(W2, b1, w2t, b1p);
  gemm1_kernel<<<dim3(15, 128), 256, 0, stream>>>(hs, w1t, b1p, h1);
  layer23_kernel<<<4096, 256, 0, stream>>>(h1, w2t, b2, W3, b3, logits);
  gather_kernel<<<64, 256, 0, stream>>>(starts, logits, out);
}

// Round 3
// 2010.060 us; speedup vs baseline: 1.8212x; 1.8212x over previous
//
#include <hip/hip_runtime.h>

typedef __attribute__((ext_vector_type(8))) short bf16x8;
typedef __attribute__((ext_vector_type(4))) float f32x4;
typedef unsigned int u32;

#define L_DIM 24
#define B_DIM 32
#define S_DIM 512
#define H_DIM 1024
#define M_DIM 16384      // B*S
#define K_DIM 24576      // L*H
#define N_REAL 900
#define NP 1024          // padded N (fast path)
#define BM 128
#define BN 128
#define BK 64

// fallback-path sizes (round-2 layout)
#define N_PAD_FB 960
#define K2_PAD_FB 912

// round-to-nearest-even fp32 -> bf16
__device__ __forceinline__ short f2bf(float f) {
  unsigned u = __builtin_bit_cast(unsigned, f);
  u += 0x7FFFu + ((u >> 16) & 1u);
  return (short)(u >> 16);
}

// =====================================================================
// FAST PATH
// =====================================================================

// ---- P0: hidden_states fp32 [L][B][S][H] -> A bf16 [M][K], pre-swizzled:
// element (m, k) stored at k' = (k & ~63) + (((k>>3 & 7) ^ (m & 7)) * 8) + (k & 7)
__global__ __launch_bounds__(256)
void conv_a_kernel(const float* __restrict__ hs, unsigned short* __restrict__ a) {
  const int m = blockIdx.x;
  const int b = m >> 9, s = m & 511;
  const int m7 = m & 7;
  unsigned short* dstRow = a + (size_t)m * K_DIM;
#pragma unroll
  for (int i = 0; i < 12; ++i) {
    const int g = threadIdx.x + i * 256;        // granule 0..3071 (8 elems each)
    const int l = g >> 7;
    const int h = (g & 127) * 8;
    const float* src = hs + (((size_t)l * B_DIM + b) * S_DIM + s) * H_DIM + h;
    float4 f0 = *(const float4*)src;
    float4 f1 = *(const float4*)(src + 4);
    bf16x8 p;
    p[0] = f2bf(f0.x); p[1] = f2bf(f0.y); p[2] = f2bf(f0.z); p[3] = f2bf(f0.w);
    p[4] = f2bf(f1.x); p[5] = f2bf(f1.y); p[6] = f2bf(f1.z); p[7] = f2bf(f1.w);
    const int slot = (g & 7) ^ m7;
    *(bf16x8*)(dstRow + (g & ~7) * 8 + slot * 8) = p;
  }
}

// ---- P1: W1 [K][900] -> W1T bf16 [1024][K], zero-padded rows, same swizzle (by n&7)
__global__ __launch_bounds__(256)
void prep_w1t_kernel(const float* __restrict__ w1, unsigned short* __restrict__ w1t) {
  __shared__ unsigned short t[64][72];
  const int n0 = blockIdx.x * 64;
  const int k0 = blockIdx.y * 64;
  const int tid = threadIdx.x;
  {
    const int nl = tid & 63;
    const int n = n0 + nl;
#pragma unroll
    for (int p = 0; p < 16; ++p) {
      const int kl = p * 4 + (tid >> 6);
      float v = (n < N_REAL) ? w1[(size_t)(k0 + kl) * N_REAL + n] : 0.f;
      t[nl][kl] = (unsigned short)f2bf(v);
    }
  }
  __syncthreads();
  {
    const int kl = tid & 63;
#pragma unroll
    for (int p = 0; p < 16; ++p) {
      const int nl2 = p * 4 + (tid >> 6);
      const int n = n0 + nl2;
      const int slot = ((kl >> 3) ^ (n & 7)) & 7;
      w1t[(size_t)n * K_DIM + k0 + slot * 8 + (kl & 7)] = t[nl2][kl];
    }
  }
}

// ---- P2: W2T fp32 [40][1024] (transposed, padded) + b1 padded [1024]
__global__ __launch_bounds__(256)
void prep_small_kernel(const float* __restrict__ w2, const float* __restrict__ b1,
                       float* __restrict__ w2t, float* __restrict__ b1p) {
  const int i = blockIdx.x * 256 + threadIdx.x;
  if (i < 40 * NP) {
    const int j = i >> 10, k = i & (NP - 1);
    w2t[i] = (k < N_REAL) ? w2[(size_t)k * 40 + j] : 0.f;
  }
  const int t2 = i - 40 * NP;
  if (t2 >= 0 && t2 < NP)
    b1p[t2] = (t2 < N_REAL) ? b1[t2] : 0.f;
}

// ---- G1: h1 = relu(A @ W1T^T + b1), pure-bf16 MFMA, global_load_lds staging
__global__ __launch_bounds__(256)
void gemm1_bf16_kernel(const unsigned short* __restrict__ a,
                       const unsigned short* __restrict__ w1t,
                       const float* __restrict__ b1p,
                       float* __restrict__ h1) {
  __shared__ __align__(16) unsigned short Ab[BM * BK];   // 16 KiB, rows of 128 B
  __shared__ __align__(16) unsigned short Bb[BN * BK];   // 16 KiB

  const int tid = threadIdx.x;
  const int lane = tid & 63;
  const int wid = tid >> 6;
  const int wr = wid >> 1;     // m-half (64 rows)
  const int wc = wid & 1;      // n-half (64 cols)

  // bijective chunked XCD swizzle: nwg=1024, 128 per XCD, n fastest within chunk
  const int hw = blockIdx.x;
  const int logical = (hw & 7) * 128 + (hw >> 3);
  const int nb = logical & 7;
  const int mb = logical >> 3;
  const int m0 = mb * BM;
  const int n0 = nb * BN;

  f32x4 acc[4][4] = {};

  const unsigned short* abase = a + (size_t)m0 * K_DIM;
  const unsigned short* bbase = w1t + (size_t)n0 * K_DIM;
  const int srow = lane >> 3;   // + 8*chunk
  const int sg = lane & 7;      // 16B granule within 128B row

  const int r15 = lane & 15;
  const int hi4 = lane >> 4;    // 0..3

  for (int k0 = 0; k0 < K_DIM; k0 += BK) {
    // stage A and B tiles: 16 chunks each of 1 KiB, 4 per wave
#pragma unroll
    for (int i = 0; i < 4; ++i) {
      const int c = wid * 4 + i;
      const int row = c * 8 + srow;
      __builtin_amdgcn_global_load_lds(
          (const __attribute__((address_space(1))) void*)(abase + (size_t)row * K_DIM + k0 + sg * 8),
          (__attribute__((address_space(3))) void*)((char*)Ab + c * 1024),
          16, 0, 0);
      __builtin_amdgcn_global_load_lds(
          (const __attribute__((address_space(1))) void*)(bbase + (size_t)row * K_DIM + k0 + sg * 8),
          (__attribute__((address_space(3))) void*)((char*)Bb + c * 1024),
          16, 0, 0);
    }
    __syncthreads();

#pragma unroll
    for (int kk = 0; kk < 2; ++kk) {
      bf16x8 av[4], bv[4];
#pragma unroll
      for (int mi = 0; mi < 4; ++mi) {
        const int row = wr * 64 + mi * 16 + r15;
        const int s = (kk * 4 + hi4) ^ (row & 7);
        av[mi] = *(const bf16x8*)((const char*)Ab + row * 128 + s * 16);
      }
#pragma unroll
      for (int ni = 0; ni < 4; ++ni) {
        const int row = wc * 64 + ni * 16 + r15;
        const int s = (kk * 4 + hi4) ^ (row & 7);
        bv[ni] = *(const bf16x8*)((const char*)Bb + row * 128 + s * 16);
      }
#pragma unroll
      for (int mi = 0; mi < 4; ++mi)
#pragma unroll
        for (int ni = 0; ni < 4; ++ni)
          acc[mi][ni] = __builtin_amdgcn_mfma_f32_16x16x32_bf16(av[mi], bv[ni], acc[mi][ni], 0, 0, 0);
    }
    __syncthreads();
  }

  // epilogue: relu(acc + b1); C/D: col = lane&15, row = (lane>>4)*4 + r
#pragma unroll
  for (int mi = 0; mi < 4; ++mi) {
#pragma unroll
    for (int ni = 0; ni < 4; ++ni) {
      const int n = n0 + wc * 64 + ni * 16 + r15;
      const float bias = b1p[n];
#pragma unroll
      for (int r = 0; r < 4; ++r) {
        const int m = m0 + wr * 64 + mi * 16 + hi4 * 4 + r;
        const float v = acc[mi][ni][r] + bias;
        h1[(size_t)m * NP + n] = v > 0.f ? v : 0.f;
      }
    }
  }
}

// ---- K2: logits = sigmoid(relu(h1 @ W2 + b2) @ W3 + b3), one wave/row (stride NP)
__global__ __launch_bounds__(256)
void layer23_kernel(const float* __restrict__ h1, const float* __restrict__ w2t,
                    const float* __restrict__ b2, const float* __restrict__ w3,
                    const float* __restrict__ b3, float* __restrict__ logits) {
  const int wave = (blockIdx.x * 256 + threadIdx.x) >> 6;
  const int lane = threadIdx.x & 63;
  const float* hrow = h1 + (size_t)wave * NP;
  float acc = 0.f;
  if (lane < 40) {
    const float* wrow = w2t + lane * NP;
    for (int k = 0; k < NP; k += 8) {
      float4 h0 = *(const float4*)(hrow + k);
      float4 h4 = *(const float4*)(hrow + k + 4);
      float4 w0 = *(const float4*)(wrow + k);
      float4 w4 = *(const float4*)(wrow + k + 4);
      acc += h0.x * w0.x + h0.y * w0.y + h0.z * w0.z + h0.w * w0.w;
      acc += h4.x * w4.x + h4.y * w4.y + h4.z * w4.z + h4.w * w4.w;
    }
    acc += b2[lane];
    acc = acc > 0.f ? acc : 0.f;
    acc *= w3[lane];
  }
#pragma unroll
  for (int off = 32; off > 0; off >>= 1)
    acc += __shfl_down(acc, off);
  if (lane == 0)
    logits[wave] = 1.f / (1.f + expf(-(acc + b3[0])));
}

// ---- K3: ragged gather (shared by both paths)
__global__ __launch_bounds__(256)
void gather_kernel(const int* __restrict__ starts, const float* __restrict__ logits,
                   float* __restrict__ out) {
  const int i = blockIdx.x * 256 + threadIdx.x;
  if (i >= M_DIM) return;
  const int st = starts[i];
  int idx = st;
  if (idx < 0) idx = 0;
  if (idx > S_DIM - 1) idx = S_DIM - 1;
  out[i] = (st != 0) ? logits[((i >> 9) << 9) + idx] : 0.f;
}

// =====================================================================
// FALLBACK PATH (round-2, known-correct; used only if ws_size too small)
// =====================================================================

__global__ __launch_bounds__(256)
void prep_w1t_fb_kernel(const float* __restrict__ w1, unsigned short* __restrict__ w1t) {
  __shared__ unsigned short t[64][72];
  const int n0 = blockIdx.x * 64;
  const int k0 = blockIdx.y * 64;
  const int tid = threadIdx.x;
  {
    const int nl = tid & 63;
    const int n = n0 + nl;
#pragma unroll
    for (int p = 0; p < 16; ++p) {
      const int kl = p * 4 + (tid >> 6);
      float v = (n < N_REAL) ? w1[(size_t)(k0 + kl) * N_REAL + n] : 0.f;
      t[nl][kl] = (unsigned short)f2bf(v);
    }
  }
  __syncthreads();
  {
    const int kl = tid & 63;
#pragma unroll
    for (int p = 0; p < 16; ++p) {
      const int nl2 = p * 4 + (tid >> 6);
      w1t[(size_t)(n0 + nl2) * K_DIM + k0 + kl] = t[nl2][kl];
    }
  }
}

__global__ __launch_bounds__(256)
void prep_small_fb_kernel(const float* __restrict__ w2, const float* __restrict__ b1,
                          float* __restrict__ w2t, float* __restrict__ b1p) {
  const int i = blockIdx.x * 256 + threadIdx.x;
  if (i < 40 * K2_PAD_FB) {
    const int j = i / K2_PAD_FB, k = i - j * K2_PAD_FB;
    w2t[i] = (k < N_REAL) ? w2[(size_t)k * 40 + j] : 0.f;
  }
  const int t2 = i - 40 * K2_PAD_FB;
  if (t2 >= 0 && t2 < N_PAD_FB)
    b1p[t2] = (t2 < N_REAL) ? b1[t2] : 0.f;
}

__global__ __launch_bounds__(256)
void gemm1_fb_kernel(const float* __restrict__ hs,
                     const unsigned short* __restrict__ w1t,
                     const float* __restrict__ b1p,
                     float* __restrict__ h1) {
  __shared__ __align__(16) unsigned short Ab[128 * 64];
  __shared__ __align__(16) unsigned short Bb[64 * 64];
  char* AbRaw = (char*)Ab;
  char* BbRaw = (char*)Bb;
  const int tid = threadIdx.x;
  const int lane = tid & 63;
  const int wid = tid >> 6;
  const int wr = wid >> 1;
  const int wc = wid & 1;
  const int m0 = blockIdx.y * 128;
  const int n0 = blockIdx.x * 64;
  f32x4 acc[4][2] = {};
  const int arow = tid >> 1;
  const int ahalf = tid & 1;
  const int am = m0 + arow;
  const size_t a_row_off = (((size_t)(am >> 9)) * S_DIM + (am & 511)) * H_DIM;
  const int brow = tid >> 2;
  const int bq = tid & 3;
  const unsigned short* w1row = w1t + (size_t)(n0 + brow) * K_DIM;

  for (int k0 = 0; k0 < K_DIM; k0 += 64) {
    {
      const int l = k0 >> 10;
      const int h0 = (k0 & 1023) + ahalf * 32;
      const float* aptr = hs + (size_t)l * (B_DIM * S_DIM * H_DIM) + a_row_off + h0;
#pragma unroll
      for (int j = 0; j < 4; ++j) {
        float4 f0 = *(const float4*)(aptr + j * 8);
        float4 f1 = *(const float4*)(aptr + j * 8 + 4);
        bf16x8 p;
        p[0] = f2bf(f0.x); p[1] = f2bf(f0.y); p[2] = f2bf(f0.z); p[3] = f2bf(f0.w);
        p[4] = f2bf(f1.x); p[5] = f2bf(f1.y); p[6] = f2bf(f1.z); p[7] = f2bf(f1.w);
        const int off = ((arow << 7) + ahalf * 64 + j * 16) ^ ((arow & 7) << 4);
        *(bf16x8*)(AbRaw + off) = p;
      }
    }
    {
      const uint4 s0 = *(const uint4*)(w1row + k0 + bq * 16);
      const uint4 s1 = *(const uint4*)(w1row + k0 + bq * 16 + 8);
      const int off0 = ((brow << 7) + bq * 32) ^ ((brow & 7) << 4);
      const int off1 = ((brow << 7) + bq * 32 + 16) ^ ((brow & 7) << 4);
      *(uint4*)(BbRaw + off0) = s0;
      *(uint4*)(BbRaw + off1) = s1;
    }
    __syncthreads();
#pragma unroll
    for (int kk = 0; kk < 2; ++kk) {
      bf16x8 a[4], b[2];
#pragma unroll
      for (int mi = 0; mi < 4; ++mi) {
        const int row = wr * 64 + mi * 16 + (lane & 15);
        const int off = ((row << 7) + kk * 64 + (lane >> 4) * 16) ^ ((row & 7) << 4);
        a[mi] = *(const bf16x8*)(AbRaw + off);
      }
#pragma unroll
      for (int ni = 0; ni < 2; ++ni) {
        const int row = wc * 32 + ni * 16 + (lane & 15);
        const int off = ((row << 7) + kk * 64 + (lane >> 4) * 16) ^ ((row & 7) << 4);
        b[ni] = *(const bf16x8*)(BbRaw + off);
      }
#pragma unroll
      for (int mi = 0; mi < 4; ++mi)
#pragma unroll
        for (int ni = 0; ni < 2; ++ni)
          acc[mi][ni] = __builtin_amdgcn_mfma_f32_16x16x32_bf16(a[mi], b[ni], acc[mi][ni], 0, 0, 0);
    }
    __syncthreads();
  }
#pragma unroll
  for (int mi = 0; mi < 4; ++mi) {
#pragma unroll
    for (int ni = 0; ni < 2; ++ni) {
      const int n = n0 + wc * 32 + ni * 16 + (lane & 15);
      const float bias = b1p[n];
#pragma unroll
      for (int r = 0; r < 4; ++r) {
        const int m = m0 + wr * 64 + mi * 16 + (lane >> 4) * 4 + r;
        const float v = acc[mi][ni][r] + bias;
        h1[(size_t)m * N_PAD_FB + n] = v > 0.f ? v : 0.f;
      }
    }
  }
}

__global__ __launch_bounds__(256)
void layer23_fb_kernel(const float* __restrict__ h1, const float* __restrict__ w2t,
                       const float* __restrict__ b2, const float* __restrict__ w3,
                       const float* __restrict__ b3, float* __restrict__ logits) {
  const int wave = (blockIdx.x * 256 + threadIdx.x) >> 6;
  const int lane = threadIdx.x & 63;
  const float* hrow = h1 + (size_t)wave * N_PAD_FB;
  float acc = 0.f;
  if (lane < 40) {
    const float* wrow = w2t + lane * K2_PAD_FB;
    for (int k = 0; k < K2_PAD_FB; k += 8) {
      float4 h0 = *(const float4*)(hrow + k);
      float4 h4 = *(const float4*)(hrow + k + 4);
      float4 w0 = *(const float4*)(wrow + k);
      float4 w4 = *(const float4*)(wrow + k + 4);
      acc += h0.x * w0.x + h0.y * w0.y + h0.z * w0.z + h0.w * w0.w;
      acc += h4.x * w4.x + h4.y * w4.y + h4.z * w4.z + h4.w * w4.w;
    }
    acc += b2[lane];
    acc = acc > 0.f ? acc : 0.f;
    acc *= w3[lane];
  }
#pragma unroll
  for (int off = 32; off > 0; off >>= 1)
    acc += __shfl_down(acc, off);
  if (lane == 0)
    logits[wave] = 1.f / (1.f + expf(-(acc + b3[0])));
}

// =====================================================================

extern "C" void kernel_launch(void* const* d_in, const int* in_sizes, int n_in,
                              void* d_out, int out_size, void* d_ws, size_t ws_size,
                              hipStream_t stream) {
  const float* hs = (const float*)d_in[0];
  const float* W1 = (const float*)d_in[1];
  const float* b1 = (const float*)d_in[2];
  const float* W2 = (const float*)d_in[3];
  const float* b2 = (const float*)d_in[4];
  const float* W3 = (const float*)d_in[5];
  const float* b3 = (const float*)d_in[6];
  const int* starts = (const int*)d_in[7];
  float* out = (float*)d_out;
  char* ws = (char*)d_ws;

  // fast-path workspace layout
  const size_t A_BYTES   = (size_t)M_DIM * K_DIM * 2;         // 805,306,368
  const size_t W1T_BYTES = (size_t)NP * K_DIM * 2;            //  50,331,648
  const size_t H1_BYTES  = (size_t)M_DIM * NP * 4;            //  67,108,864
  const size_t W2T_BYTES = 40 * NP * 4;                       //     163,840
  const size_t B1P_BYTES = NP * 4;                            //       4,096
  const size_t LG_BYTES  = M_DIM * 4;                         //      65,536
  const size_t FAST_NEED = A_BYTES + W1T_BYTES + H1_BYTES + W2T_BYTES + B1P_BYTES + LG_BYTES;

  if (ws_size >= FAST_NEED) {
    unsigned short* a    = (unsigned short*)ws;
    unsigned short* w1t  = (unsigned short*)(ws + A_BYTES);
    float* h1            = (float*)(ws + A_BYTES + W1T_BYTES);
    float* w2t           = (float*)(ws + A_BYTES + W1T_BYTES + H1_BYTES);
    float* b1p           = (float*)(ws + A_BYTES + W1T_BYTES + H1_BYTES + W2T_BYTES);
    float* logits        = (float*)(ws + A_BYTES + W1T_BYTES + H1_BYTES + W2T_BYTES + B1P_BYTES);

    conv_a_kernel<<<M_DIM, 256, 0, stream>>>(hs, a);
    prep_w1t_kernel<<<dim3(16, 384), 256, 0, stream>>>(W1, w1t);
    prep_small_kernel<<<164, 256, 0, stream>>>(W2, b1, w2t, b1p);
    gemm1_bf16_kernel<<<1024, 256, 0, stream>>>(a, w1t, b1p, h1);
    layer23_kernel<<<4096, 256, 0, stream>>>(h1, w2t, b2, W3, b3, logits);
    gather_kernel<<<64, 256, 0, stream>>>(starts, logits, out);
  } else {
    unsigned short* w1t = (unsigned short*)ws;                              // 45 MB (960*K*2 = 47,185,920)
    float* h1 = (float*)(ws + 47185920);                                    // 62,914,560
    float* w2t = (float*)(ws + 47185920 + 62914560);                        // 145,920
    float* b1p = (float*)(ws + 47185920 + 62914560 + 145920);               // 3,840
    float* logits = (float*)(ws + 47185920 + 62914560 + 145920 + 3840);     // 65,536

    prep_w1t_fb_kernel<<<dim3(15, 384), 256, 0, stream>>>(W1, w1t);
    prep_small_fb_kernel<<<147, 256, 0, stream>>>(W2, b1, w2t, b1p);
    gemm1_fb_kernel<<<dim3(15, 128), 256, 0, stream>>>(hs, w1t, b1p, h1);
    layer23_fb_kernel<<<4096, 256, 0, stream>>>(h1, w2t, b2, W3, b3, logits);
    gather_kernel<<<64, 256, 0, stream>>>(starts, logits, out);
  }
}

// Round 4
// 1762.308 us; speedup vs baseline: 2.0772x; 1.1406x over previous
//
#include <hip/hip_runtime.h>

typedef __attribute__((ext_vector_type(8))) short bf16x8;
typedef __attribute__((ext_vector_type(4))) float f32x4;

#define L_DIM 24
#define B_DIM 32
#define S_DIM 512
#define H_DIM 1024
#define M_DIM 16384      // B*S
#define K_DIM 24576      // L*H
#define N_REAL 900
#define NP 1024          // padded N (fast path)
#define NT 384           // K tiles of 64

// fallback-path sizes (round-2 layout)
#define N_PAD_FB 960
#define K2_PAD_FB 912

// round-to-nearest-even fp32 -> bf16
__device__ __forceinline__ short f2bf(float f) {
  unsigned u = __builtin_bit_cast(unsigned, f);
  u += 0x7FFFu + ((u >> 16) & 1u);
  return (short)(u >> 16);
}

// =====================================================================
// FAST PATH
// =====================================================================

// ---- P0: hidden_states fp32 [L][B][S][H] -> A bf16 [M][K], pre-swizzled:
// element (m, k) stored at k' = (k & ~63) + (((k>>3 & 7) ^ (m & 7)) * 8) + (k & 7)
__global__ __launch_bounds__(256)
void conv_a_kernel(const float* __restrict__ hs, unsigned short* __restrict__ a) {
  const int m = blockIdx.x;
  const int b = m >> 9, s = m & 511;
  const int m7 = m & 7;
  unsigned short* dstRow = a + (size_t)m * K_DIM;
#pragma unroll
  for (int i = 0; i < 12; ++i) {
    const int g = threadIdx.x + i * 256;        // granule 0..3071 (8 elems each)
    const int l = g >> 7;
    const int h = (g & 127) * 8;
    const float* src = hs + (((size_t)l * B_DIM + b) * S_DIM + s) * H_DIM + h;
    float4 f0 = *(const float4*)src;
    float4 f1 = *(const float4*)(src + 4);
    bf16x8 p;
    p[0] = f2bf(f0.x); p[1] = f2bf(f0.y); p[2] = f2bf(f0.z); p[3] = f2bf(f0.w);
    p[4] = f2bf(f1.x); p[5] = f2bf(f1.y); p[6] = f2bf(f1.z); p[7] = f2bf(f1.w);
    const int slot = (g & 7) ^ m7;
    *(bf16x8*)(dstRow + (g & ~7) * 8 + slot * 8) = p;
  }
}

// ---- P1: W1 [K][900] -> W1T bf16 [1024][K], zero-padded rows, same swizzle (by n&7)
__global__ __launch_bounds__(256)
void prep_w1t_kernel(const float* __restrict__ w1, unsigned short* __restrict__ w1t) {
  __shared__ unsigned short t[64][72];
  const int n0 = blockIdx.x * 64;
  const int k0 = blockIdx.y * 64;
  const int tid = threadIdx.x;
  {
    const int nl = tid & 63;
    const int n = n0 + nl;
#pragma unroll
    for (int p = 0; p < 16; ++p) {
      const int kl = p * 4 + (tid >> 6);
      float v = (n < N_REAL) ? w1[(size_t)(k0 + kl) * N_REAL + n] : 0.f;
      t[nl][kl] = (unsigned short)f2bf(v);
    }
  }
  __syncthreads();
  {
    const int kl = tid & 63;
#pragma unroll
    for (int p = 0; p < 16; ++p) {
      const int nl2 = p * 4 + (tid >> 6);
      const int n = n0 + nl2;
      const int slot = ((kl >> 3) ^ (n & 7)) & 7;
      w1t[(size_t)n * K_DIM + k0 + slot * 8 + (kl & 7)] = t[nl2][kl];
    }
  }
}

// ---- P2: W2T fp32 [40][1024] (transposed, padded) + b1 padded [1024]
__global__ __launch_bounds__(256)
void prep_small_kernel(const float* __restrict__ w2, const float* __restrict__ b1,
                       float* __restrict__ w2t, float* __restrict__ b1p) {
  const int i = blockIdx.x * 256 + threadIdx.x;
  if (i < 40 * NP) {
    const int j = i >> 10, k = i & (NP - 1);
    w2t[i] = (k < N_REAL) ? w2[(size_t)k * 40 + j] : 0.f;
  }
  const int t2 = i - 40 * NP;
  if (t2 >= 0 && t2 < NP)
    b1p[t2] = (t2 < N_REAL) ? b1[t2] : 0.f;
}

// ---- G1: h1 = relu(A @ W1T^T + b1), 256x256 tile, 8-phase counted-vmcnt schedule
#define SBAR() do { __builtin_amdgcn_sched_barrier(0); __builtin_amdgcn_s_barrier(); __builtin_amdgcn_sched_barrier(0); } while (0)
#define WAIT_LGKM0() do { asm volatile("s_waitcnt lgkmcnt(0)" ::: "memory"); __builtin_amdgcn_sched_barrier(0); } while (0)
#define VMWAIT(N) do { asm volatile("s_waitcnt vmcnt(" #N ")" ::: "memory"); __builtin_amdgcn_sched_barrier(0); } while (0)

// stage one 128-row half-tile (16 KiB) cooperatively: 2 x global_load_lds per thread
#define STAGE(DSTREG, GBASE, ROWBASE, HALF, TK) do {                                   \
  _Pragma("unroll")                                                                    \
  for (int _i = 0; _i < 2; ++_i) {                                                     \
    const int _ch = wid * 2 + _i;                                                      \
    const int _row = (HALF) * 128 + _ch * 8 + (lane >> 3);                             \
    __builtin_amdgcn_global_load_lds(                                                  \
      (const __attribute__((address_space(1))) void*)((GBASE) +                        \
          (size_t)((ROWBASE) + _row) * K_DIM + (TK) * 64 + (lane & 7) * 8),            \
      (__attribute__((address_space(3))) void*)((DSTREG) + (HALF) * 16384 + _ch * 1024), \
      16, 0, 0);                                                                       \
  }                                                                                    \
} while (0)

#define LDA4(AV, MIBASE, ABUF) do {                                                    \
  _Pragma("unroll")                                                                    \
  for (int _mi = 0; _mi < 4; ++_mi) {                                                  \
    _Pragma("unroll")                                                                  \
    for (int _kk = 0; _kk < 2; ++_kk) {                                                \
      const int _r = wr * 128 + ((MIBASE) + _mi) * 16 + r15;                           \
      AV[_mi][_kk] = *(const bf16x8*)((ABUF) + _r * 128 + (((_kk)*4 + hi4) ^ (_r & 7)) * 16); \
    }                                                                                  \
  }                                                                                    \
} while (0)

#define LDB2(BV, NIBASE, BBUF) do {                                                    \
  _Pragma("unroll")                                                                    \
  for (int _ni = 0; _ni < 2; ++_ni) {                                                  \
    _Pragma("unroll")                                                                  \
    for (int _kk = 0; _kk < 2; ++_kk) {                                                \
      const int _r = wc * 64 + ((NIBASE) + _ni) * 16 + r15;                            \
      BV[_ni][_kk] = *(const bf16x8*)((BBUF) + _r * 128 + (((_kk)*4 + hi4) ^ (_r & 7)) * 16); \
    }                                                                                  \
  }                                                                                    \
} while (0)

#define MFMA_Q(AV, BV, MIBASE, NIBASE) do {                                            \
  _Pragma("unroll")                                                                    \
  for (int _mi = 0; _mi < 4; ++_mi)                                                    \
    _Pragma("unroll")                                                                  \
    for (int _ni = 0; _ni < 2; ++_ni)                                                  \
      _Pragma("unroll")                                                                \
      for (int _kk = 0; _kk < 2; ++_kk)                                                \
        acc[(MIBASE) + _mi][(NIBASE) + _ni] = __builtin_amdgcn_mfma_f32_16x16x32_bf16( \
            AV[_mi][_kk], BV[_ni][_kk], acc[(MIBASE) + _mi][(NIBASE) + _ni], 0, 0, 0); \
} while (0)

// one K-tile = 4 phases. SA: stage A halves of tile T+1 (into other buffer).
// SB: stage B halves of tile T+2 (into this buffer). WAITSTMT: vmcnt wait at ph4.
#define TILE_BODY(T, ABUF, BBUF, ABUFN, SA, SB, WAITSTMT) do {                         \
  /* ---- phase 1 ---- */                                                              \
  LDA4(av, 0, (ABUF));                                                                 \
  LDB2(bv0, 0, (BBUF));                                                                \
  if (SA) STAGE((ABUFN), a, m0, 0, (T) + 1);                                           \
  SBAR();                                                                              \
  WAIT_LGKM0();                                                                        \
  __builtin_amdgcn_s_setprio(1);                                                       \
  MFMA_Q(av, bv0, 0, 0);                                                               \
  __builtin_amdgcn_s_setprio(0);                                                       \
  SBAR();                                                                              \
  /* ---- phase 2 ---- */                                                              \
  LDB2(bv1, 2, (BBUF));                                                                \
  if (SA) STAGE((ABUFN), a, m0, 1, (T) + 1);                                           \
  SBAR();                                                                              \
  WAIT_LGKM0();                                                                        \
  __builtin_amdgcn_s_setprio(1);                                                       \
  MFMA_Q(av, bv1, 0, 2);                                                               \
  __builtin_amdgcn_s_setprio(0);                                                       \
  SBAR();                                                                              \
  /* ---- phase 3 ---- */                                                              \
  LDA4(av, 4, (ABUF));                                                                 \
  if (SB) STAGE((BBUF), w1t, n0, 0, (T) + 2);                                          \
  SBAR();                                                                              \
  WAIT_LGKM0();                                                                        \
  __builtin_amdgcn_s_setprio(1);                                                       \
  MFMA_Q(av, bv1, 4, 2);                                                               \
  __builtin_amdgcn_s_setprio(0);                                                       \
  SBAR();                                                                              \
  /* ---- phase 4 ---- */                                                              \
  if (SB) STAGE((BBUF), w1t, n0, 1, (T) + 2);                                          \
  SBAR();                                                                              \
  WAIT_LGKM0();                                                                        \
  __builtin_amdgcn_s_setprio(1);                                                       \
  MFMA_Q(av, bv0, 4, 0);                                                               \
  __builtin_amdgcn_s_setprio(0);                                                       \
  WAITSTMT;                                                                            \
  SBAR();                                                                              \
} while (0)

__global__ __launch_bounds__(512, 2)
void gemm1_8ph_kernel(const unsigned short* __restrict__ a,
                      const unsigned short* __restrict__ w1t,
                      const float* __restrict__ b1p,
                      float* __restrict__ h1) {
  extern __shared__ char L[];   // 128 KiB: [buf][A 32K | B 32K]
  char* const A0 = L;
  char* const B0 = L + 32768;
  char* const A1 = L + 65536;
  char* const B1 = L + 65536 + 32768;

  const int tid = threadIdx.x;
  const int lane = tid & 63;
  const int wid = tid >> 6;          // 0..7
  const int wr = wid >> 2;           // 0..1 (128-row band)
  const int wc = wid & 3;            // 0..3 (64-col band)
  const int r15 = lane & 15;
  const int hi4 = lane >> 4;         // 0..3

  // bijective XCD mapping: xcd = hw&7 gets m-panels [xcd*8, xcd*8+8) x all 4 n-blocks
  const int hw = blockIdx.x;
  const int mb = (hw & 7) * 8 + (hw >> 5);
  const int nb = (hw >> 3) & 3;
  const int m0 = mb * 256;
  const int n0 = nb * 256;

  f32x4 acc[8][4] = {};
  bf16x8 av[4][2], bv0[2][2], bv1[2][2];

  // prologue: tile0 (A+B) + tile1 B = 12 loads/thread; wait all but last 4
  STAGE(A0, a, m0, 0, 0);
  STAGE(A0, a, m0, 1, 0);
  STAGE(B0, w1t, n0, 0, 0);
  STAGE(B0, w1t, n0, 1, 0);
  STAGE(B1, w1t, n0, 0, 1);
  STAGE(B1, w1t, n0, 1, 1);
  VMWAIT(4);
  SBAR();

  for (int kt = 0; kt < 191; ++kt) {
    const int t = 2 * kt;
    TILE_BODY(t,     A0, B0, A1, 1, 1, VMWAIT(4));
    TILE_BODY(t + 1, A1, B1, A0, 1, 1, VMWAIT(4));
  }
  // peeled tail: tiles 382, 383
  TILE_BODY(382, A0, B0, A1, 1, 0, VMWAIT(0));
  TILE_BODY(383, A1, B1, A0, 0, 0, (void)0);

  // epilogue: relu(acc + b1); C/D: col = lane&15, row = (lane>>4)*4 + r
#pragma unroll
  for (int mi = 0; mi < 8; ++mi) {
#pragma unroll
    for (int ni = 0; ni < 4; ++ni) {
      const int n = n0 + wc * 64 + ni * 16 + r15;
      const float bias = b1p[n];
#pragma unroll
      for (int r = 0; r < 4; ++r) {
        const int m = m0 + wr * 128 + mi * 16 + hi4 * 4 + r;
        const float v = acc[mi][ni][r] + bias;
        h1[(size_t)m * NP + n] = v > 0.f ? v : 0.f;
      }
    }
  }
}

// ---- K2: logits = sigmoid(relu(h1 @ W2 + b2) @ W3 + b3), one wave/row (stride NP)
__global__ __launch_bounds__(256)
void layer23_kernel(const float* __restrict__ h1, const float* __restrict__ w2t,
                    const float* __restrict__ b2, const float* __restrict__ w3,
                    const float* __restrict__ b3, float* __restrict__ logits) {
  const int wave = (blockIdx.x * 256 + threadIdx.x) >> 6;
  const int lane = threadIdx.x & 63;
  const float* hrow = h1 + (size_t)wave * NP;
  float acc = 0.f;
  if (lane < 40) {
    const float* wrow = w2t + lane * NP;
    for (int k = 0; k < NP; k += 8) {
      float4 h0 = *(const float4*)(hrow + k);
      float4 h4 = *(const float4*)(hrow + k + 4);
      float4 w0 = *(const float4*)(wrow + k);
      float4 w4 = *(const float4*)(wrow + k + 4);
      acc += h0.x * w0.x + h0.y * w0.y + h0.z * w0.z + h0.w * w0.w;
      acc += h4.x * w4.x + h4.y * w4.y + h4.z * w4.z + h4.w * w4.w;
    }
    acc += b2[lane];
    acc = acc > 0.f ? acc : 0.f;
    acc *= w3[lane];
  }
#pragma unroll
  for (int off = 32; off > 0; off >>= 1)
    acc += __shfl_down(acc, off);
  if (lane == 0)
    logits[wave] = 1.f / (1.f + expf(-(acc + b3[0])));
}

// ---- K3: ragged gather (shared by both paths)
__global__ __launch_bounds__(256)
void gather_kernel(const int* __restrict__ starts, const float* __restrict__ logits,
                   float* __restrict__ out) {
  const int i = blockIdx.x * 256 + threadIdx.x;
  if (i >= M_DIM) return;
  const int st = starts[i];
  int idx = st;
  if (idx < 0) idx = 0;
  if (idx > S_DIM - 1) idx = S_DIM - 1;
  out[i] = (st != 0) ? logits[((i >> 9) << 9) + idx] : 0.f;
}

// =====================================================================
// FALLBACK PATH (round-2, known-correct; used only if ws_size too small)
// =====================================================================

__global__ __launch_bounds__(256)
void prep_w1t_fb_kernel(const float* __restrict__ w1, unsigned short* __restrict__ w1t) {
  __shared__ unsigned short t[64][72];
  const int n0 = blockIdx.x * 64;
  const int k0 = blockIdx.y * 64;
  const int tid = threadIdx.x;
  {
    const int nl = tid & 63;
    const int n = n0 + nl;
#pragma unroll
    for (int p = 0; p < 16; ++p) {
      const int kl = p * 4 + (tid >> 6);
      float v = (n < N_REAL) ? w1[(size_t)(k0 + kl) * N_REAL + n] : 0.f;
      t[nl][kl] = (unsigned short)f2bf(v);
    }
  }
  __syncthreads();
  {
    const int kl = tid & 63;
#pragma unroll
    for (int p = 0; p < 16; ++p) {
      const int nl2 = p * 4 + (tid >> 6);
      w1t[(size_t)(n0 + nl2) * K_DIM + k0 + kl] = t[nl2][kl];
    }
  }
}

__global__ __launch_bounds__(256)
void prep_small_fb_kernel(const float* __restrict__ w2, const float* __restrict__ b1,
                          float* __restrict__ w2t, float* __restrict__ b1p) {
  const int i = blockIdx.x * 256 + threadIdx.x;
  if (i < 40 * K2_PAD_FB) {
    const int j = i / K2_PAD_FB, k = i - j * K2_PAD_FB;
    w2t[i] = (k < N_REAL) ? w2[(size_t)k * 40 + j] : 0.f;
  }
  const int t2 = i - 40 * K2_PAD_FB;
  if (t2 >= 0 && t2 < N_PAD_FB)
    b1p[t2] = (t2 < N_REAL) ? b1[t2] : 0.f;
}

__global__ __launch_bounds__(256)
void gemm1_fb_kernel(const float* __restrict__ hs,
                     const unsigned short* __restrict__ w1t,
                     const float* __restrict__ b1p,
                     float* __restrict__ h1) {
  __shared__ __align__(16) unsigned short Ab[128 * 64];
  __shared__ __align__(16) unsigned short Bb[64 * 64];
  char* AbRaw = (char*)Ab;
  char* BbRaw = (char*)Bb;
  const int tid = threadIdx.x;
  const int lane = tid & 63;
  const int wid = tid >> 6;
  const int wr = wid >> 1;
  const int wc = wid & 1;
  const int m0 = blockIdx.y * 128;
  const int n0 = blockIdx.x * 64;
  f32x4 acc[4][2] = {};
  const int arow = tid >> 1;
  const int ahalf = tid & 1;
  const int am = m0 + arow;
  const size_t a_row_off = (((size_t)(am >> 9)) * S_DIM + (am & 511)) * H_DIM;
  const int brow = tid >> 2;
  const int bq = tid & 3;
  const unsigned short* w1row = w1t + (size_t)(n0 + brow) * K_DIM;

  for (int k0 = 0; k0 < K_DIM; k0 += 64) {
    {
      const int l = k0 >> 10;
      const int h0 = (k0 & 1023) + ahalf * 32;
      const float* aptr = hs + (size_t)l * (B_DIM * S_DIM * H_DIM) + a_row_off + h0;
#pragma unroll
      for (int j = 0; j < 4; ++j) {
        float4 f0 = *(const float4*)(aptr + j * 8);
        float4 f1 = *(const float4*)(aptr + j * 8 + 4);
        bf16x8 p;
        p[0] = f2bf(f0.x); p[1] = f2bf(f0.y); p[2] = f2bf(f0.z); p[3] = f2bf(f0.w);
        p[4] = f2bf(f1.x); p[5] = f2bf(f1.y); p[6] = f2bf(f1.z); p[7] = f2bf(f1.w);
        const int off = ((arow << 7) + ahalf * 64 + j * 16) ^ ((arow & 7) << 4);
        *(bf16x8*)(AbRaw + off) = p;
      }
    }
    {
      const uint4 s0 = *(const uint4*)(w1row + k0 + bq * 16);
      const uint4 s1 = *(const uint4*)(w1row + k0 + bq * 16 + 8);
      const int off0 = ((brow << 7) + bq * 32) ^ ((brow & 7) << 4);
      const int off1 = ((brow << 7) + bq * 32 + 16) ^ ((brow & 7) << 4);
      *(uint4*)(BbRaw + off0) = s0;
      *(uint4*)(BbRaw + off1) = s1;
    }
    __syncthreads();
#pragma unroll
    for (int kk = 0; kk < 2; ++kk) {
      bf16x8 a[4], b[2];
#pragma unroll
      for (int mi = 0; mi < 4; ++mi) {
        const int row = wr * 64 + mi * 16 + (lane & 15);
        const int off = ((row << 7) + kk * 64 + (lane >> 4) * 16) ^ ((row & 7) << 4);
        a[mi] = *(const bf16x8*)(AbRaw + off);
      }
#pragma unroll
      for (int ni = 0; ni < 2; ++ni) {
        const int row = wc * 32 + ni * 16 + (lane & 15);
        const int off = ((row << 7) + kk * 64 + (lane >> 4) * 16) ^ ((row & 7) << 4);
        b[ni] = *(const bf16x8*)(BbRaw + off);
      }
#pragma unroll
      for (int mi = 0; mi < 4; ++mi)
#pragma unroll
        for (int ni = 0; ni < 2; ++ni)
          acc[mi][ni] = __builtin_amdgcn_mfma_f32_16x16x32_bf16(a[mi], b[ni], acc[mi][ni], 0, 0, 0);
    }
    __syncthreads();
  }
#pragma unroll
  for (int mi = 0; mi < 4; ++mi) {
#pragma unroll
    for (int ni = 0; ni < 2; ++ni) {
      const int n = n0 + wc * 32 + ni * 16 + (lane & 15);
      const float bias = b1p[n];
#pragma unroll
      for (int r = 0; r < 4; ++r) {
        const int m = m0 + wr * 64 + mi * 16 + (lane >> 4) * 4 + r;
        const float v = acc[mi][ni][r] + bias;
        h1[(size_t)m * N_PAD_FB + n] = v > 0.f ? v : 0.f;
      }
    }
  }
}

__global__ __launch_bounds__(256)
void layer23_fb_kernel(const float* __restrict__ h1, const float* __restrict__ w2t,
                       const float* __restrict__ b2, const float* __restrict__ w3,
                       const float* __restrict__ b3, float* __restrict__ logits) {
  const int wave = (blockIdx.x * 256 + threadIdx.x) >> 6;
  const int lane = threadIdx.x & 63;
  const float* hrow = h1 + (size_t)wave * N_PAD_FB;
  float acc = 0.f;
  if (lane < 40) {
    const float* wrow = w2t + lane * K2_PAD_FB;
    for (int k = 0; k < K2_PAD_FB; k += 8) {
      float4 h0 = *(const float4*)(hrow + k);
      float4 h4 = *(const float4*)(hrow + k + 4);
      float4 w0 = *(const float4*)(wrow + k);
      float4 w4 = *(const float4*)(wrow + k + 4);
      acc += h0.x * w0.x + h0.y * w0.y + h0.z * w0.z + h0.w * w0.w;
      acc += h4.x * w4.x + h4.y * w4.y + h4.z * w4.z + h4.w * w4.w;
    }
    acc += b2[lane];
    acc = acc > 0.f ? acc : 0.f;
    acc *= w3[lane];
  }
#pragma unroll
  for (int off = 32; off > 0; off >>= 1)
    acc += __shfl_down(acc, off);
  if (lane == 0)
    logits[wave] = 1.f / (1.f + expf(-(acc + b3[0])));
}

// =====================================================================

extern "C" void kernel_launch(void* const* d_in, const int* in_sizes, int n_in,
                              void* d_out, int out_size, void* d_ws, size_t ws_size,
                              hipStream_t stream) {
  const float* hs = (const float*)d_in[0];
  const float* W1 = (const float*)d_in[1];
  const float* b1 = (const float*)d_in[2];
  const float* W2 = (const float*)d_in[3];
  const float* b2 = (const float*)d_in[4];
  const float* W3 = (const float*)d_in[5];
  const float* b3 = (const float*)d_in[6];
  const int* starts = (const int*)d_in[7];
  float* out = (float*)d_out;
  char* ws = (char*)d_ws;

  // fast-path workspace layout
  const size_t A_BYTES   = (size_t)M_DIM * K_DIM * 2;         // 805,306,368
  const size_t W1T_BYTES = (size_t)NP * K_DIM * 2;            //  50,331,648
  const size_t H1_BYTES  = (size_t)M_DIM * NP * 4;            //  67,108,864
  const size_t W2T_BYTES = 40 * NP * 4;
  const size_t B1P_BYTES = NP * 4;
  const size_t LG_BYTES  = M_DIM * 4;
  const size_t FAST_NEED = A_BYTES + W1T_BYTES + H1_BYTES + W2T_BYTES + B1P_BYTES + LG_BYTES;

  if (ws_size >= FAST_NEED) {
    unsigned short* a    = (unsigned short*)ws;
    unsigned short* w1t  = (unsigned short*)(ws + A_BYTES);
    float* h1            = (float*)(ws + A_BYTES + W1T_BYTES);
    float* w2t           = (float*)(ws + A_BYTES + W1T_BYTES + H1_BYTES);
    float* b1p           = (float*)(ws + A_BYTES + W1T_BYTES + H1_BYTES + W2T_BYTES);
    float* logits        = (float*)(ws + A_BYTES + W1T_BYTES + H1_BYTES + W2T_BYTES + B1P_BYTES);

    hipFuncSetAttribute((const void*)gemm1_8ph_kernel,
                        hipFuncAttributeMaxDynamicSharedMemorySize, 131072);

    conv_a_kernel<<<M_DIM, 256, 0, stream>>>(hs, a);
    prep_w1t_kernel<<<dim3(16, 384), 256, 0, stream>>>(W1, w1t);
    prep_small_kernel<<<164, 256, 0, stream>>>(W2, b1, w2t, b1p);
    gemm1_8ph_kernel<<<256, 512, 131072, stream>>>(a, w1t, b1p, h1);
    layer23_kernel<<<4096, 256, 0, stream>>>(h1, w2t, b2, W3, b3, logits);
    gather_kernel<<<64, 256, 0, stream>>>(starts, logits, out);
  } else {
    unsigned short* w1t = (unsigned short*)ws;
    float* h1 = (float*)(ws + 47185920);
    float* w2t = (float*)(ws + 47185920 + 62914560);
    float* b1p = (float*)(ws + 47185920 + 62914560 + 145920);
    float* logits = (float*)(ws + 47185920 + 62914560 + 145920 + 3840);

    prep_w1t_fb_kernel<<<dim3(15, 384), 256, 0, stream>>>(W1, w1t);
    prep_small_fb_kernel<<<147, 256, 0, stream>>>(W2, b1, w2t, b1p);
    gemm1_fb_kernel<<<dim3(15, 128), 256, 0, stream>>>(hs, w1t, b1p, h1);
    layer23_fb_kernel<<<4096, 256, 0, stream>>>(h1, w2t, b2, W3, b3, logits);
    gather_kernel<<<64, 256, 0, stream>>>(starts, logits, out);
  }
}